// Round 1
// baseline (408.993 us; speedup 1.0000x reference)
//
#include <hip/hip_runtime.h>

#define D 128
#define LSTR 132   // padded LDS row stride (floats)
#define HB 256     // degree-histogram block count

typedef __attribute__((ext_vector_type(8))) short short8;
typedef __attribute__((ext_vector_type(4))) float f32x4;

static __device__ __forceinline__ unsigned short f2bf(float f) {
    unsigned u = __float_as_uint(f);
    return (unsigned short)((u + 0x7fffu + ((u >> 16) & 1u)) >> 16);  // RNE
}

// ---------------------------------------------------------------------------
// GraphSAGE (mean) x2 + head. bf16 features (fp32 accumulate).
// Row-sorted CSR via global-atomic counting sort (3 passes, no G matrix):
//   P1 prep+hist: cast x->bf16, transpose weights; atomicAdd degree hist
//   P2 scan: single-block scan of deg -> cursor[N] (row start), tile_base[],
//            invL_g[N] = 1/max(deg,1)
//   P3 fill: pos = atomicAdd(&cursor[dst]) -> csr[pos] = src | dst<<16
//            (csr comes out globally row-sorted; sortT pass eliminated)
// sage: segmented register gather over row-sorted csr + MFMA dual GEMM.
//   Gather keeps raw uint2 bf16 payloads in registers (2 VGPR/edge) and
//   prefetches next batch's csr words -> 8 feature loads in flight per group.
// d_ws: deg[Npad] | cursor[Npad] | tile_base[2052] | invL_g[Npad] | csr[Epad]
//       | xb bf16[N*D] | hb bf16[N*D] | Bt1 bf16[128*256] | Bt2 bf16[128*256]
// ---------------------------------------------------------------------------

// Blocks [0, HB): global-atomic degree histogram. Blocks [HB, ...): prep.
__global__ __launch_bounds__(256) void prep_hist_kernel(
    const float* __restrict__ x, const float* __restrict__ W1l,
    const float* __restrict__ W1r, const float* __restrict__ W2l,
    const float* __restrict__ W2r, unsigned* __restrict__ xb2,
    unsigned short* __restrict__ Bt1, unsigned short* __restrict__ Bt2,
    int NX2, const int* __restrict__ dst, int E, int* __restrict__ deg) {
    const int t = threadIdx.x;
    if (blockIdx.x < HB) {
        const int per = (E + HB - 1) / HB;
        const int lo = blockIdx.x * per;
        const int hi = min(lo + per, E);
        for (int i = lo + t; i < hi; i += 256) atomicAdd(&deg[dst[i]], 1);
        return;
    }
    const int i = (blockIdx.x - HB) * 256 + t;
    if (i < NX2) {
        const float2 v = *(const float2*)(x + 2 * (size_t)i);
        xb2[i] = (unsigned)f2bf(v.x) | ((unsigned)f2bf(v.y) << 16);
    } else if (i < NX2 + 2 * 32768) {
        const int j = i - NX2;
        const int which = j >> 15;  // 0 -> layer1, 1 -> layer2
        const int jj = j & 32767;
        const int n = jj >> 8;
        const int k = jj & 255;
        const float* Wl = which ? W2l : W1l;
        const float* Wr = which ? W2r : W1r;
        const float w = (k < 128) ? Wl[k * 128 + n] : Wr[(k - 128) * 128 + n];
        (which ? Bt2 : Bt1)[jj] = f2bf(w);
    }
}

// Single-block scan of deg -> cursor (row start offsets), tile_base, invL.
__global__ __launch_bounds__(1024) void scan_kernel(
    const int* __restrict__ deg, int N, int E, int nbins,
    int* __restrict__ cursor, int* __restrict__ tile_base,
    float* __restrict__ invL_g) {
    __shared__ int part[1024];
    const int t = threadIdx.x;
    const int chunk = (N + 1023) >> 10;
    const int lo = min(t * chunk, N);
    const int hi = min(lo + chunk, N);
    int s = 0;
    for (int i = lo; i < hi; ++i) s += deg[i];
    part[t] = s;
    __syncthreads();
    for (int off = 1; off < 1024; off <<= 1) {
        int add = (t >= off) ? part[t - off] : 0;
        __syncthreads();
        part[t] += add;
        __syncthreads();
    }
    int run = (t == 0) ? 0 : part[t - 1];
    for (int i = lo; i < hi; ++i) {
        cursor[i] = run;
        if ((i & 31) == 0) tile_base[i >> 5] = run;
        const int d = deg[i];
        invL_g[i] = 1.0f / fmaxf((float)d, 1.0f);
        run += d;
    }
    if (t == 0) tile_base[nbins] = E;
}

// Scatter edges straight to final row-sorted position via atomic rank.
__global__ __launch_bounds__(256) void fill_kernel(
    const int* __restrict__ src, const int* __restrict__ dst, int E,
    int* __restrict__ cursor, unsigned* __restrict__ csr) {
    const int i = blockIdx.x * 256 + threadIdx.x;
    if (i < E) {
        const int d = dst[i];
        const int pos = atomicAdd(&cursor[d], 1);
        csr[pos] = (unsigned)src[i] | ((unsigned)d << 16);
    }
}

// Fused: segmented bf16 gather (fp32 acc into LDS) -> MFMA dual GEMM with
// mean applied at A-frag build. HEAD folds the Linear(128,1).
template <bool HEAD>
__global__ __launch_bounds__(256, 4) void sage_kernel(
    const unsigned short* __restrict__ xb, const unsigned* __restrict__ csr,
    const int* __restrict__ tile_base, const float* __restrict__ invL_g,
    const unsigned short* __restrict__ Bt,  // [128 n][256 k] bf16
    const float* __restrict__ bl, const float* __restrict__ Wout,
    const float* __restrict__ bout, unsigned short* __restrict__ hb_out,
    float* __restrict__ out, int N) {
    __shared__ float aggL[32 * LSTR];
    __shared__ float invL[32];
    __shared__ float redH[64];

    const int b = blockIdx.x;
    const int i0 = b * 32;
    const int t = threadIdx.x;
    const int g = t >> 5;
    const int l = t & 31;
    const int c4 = l << 2;

    for (int i = t; i < 32 * LSTR; i += 256) aggL[i] = 0.f;
    if (t < 32) invL[t] = (i0 + t < N) ? invL_g[i0 + t] : 1.0f;
    __syncthreads();

    // ---- segmented edge-parallel aggregation over row-sorted csr ----
    const int rs0 = tile_base[b];
    const int re0 = tile_base[b + 1];
    const int nE = re0 - rs0;
    int e = rs0 + ((nE * g) >> 3);
    const int ee = rs0 + ((nE * (g + 1)) >> 3);

    float4 acc = make_float4(0.f, 0.f, 0.f, 0.f);
    int cur = -1;

    auto flush = [&]() {
        float* q = aggL + cur * LSTR + c4;
        atomicAdd(q + 0, acc.x);
        atomicAdd(q + 1, acc.y);
        atomicAdd(q + 2, acc.z);
        atomicAdd(q + 3, acc.w);
    };
    auto step = [&](unsigned p, uint2 u) {
        const int r = (int)(p >> 16) - i0;
        if (r != cur) {
            if (cur >= 0) flush();
            acc = make_float4(0.f, 0.f, 0.f, 0.f);
            cur = r;
        }
        acc.x += __uint_as_float(u.x << 16);
        acc.y += __uint_as_float(u.x & 0xffff0000u);
        acc.z += __uint_as_float(u.y << 16);
        acc.w += __uint_as_float(u.y & 0xffff0000u);
    };

    const int nfull = (ee - e) >> 3;
    unsigned pc[8];
    if (nfull > 0) {
#pragma unroll
        for (int i = 0; i < 8; ++i) pc[i] = csr[e + i];
    }
    for (int k = 0; k < nfull; ++k) {
        // issue all 8 feature loads (raw uint2, 2 VGPR each) ...
        uint2 u[8];
#pragma unroll
        for (int i = 0; i < 8; ++i)
            u[i] = *(const uint2*)(xb + (size_t)(pc[i] & 0xffffu) * D + c4);
        // ... then prefetch next batch's csr words ...
        unsigned pf[8];
        if (k + 1 < nfull) {
#pragma unroll
            for (int i = 0; i < 8; ++i) pf[i] = csr[e + 8 + i];
        }
        // ... then consume.
#pragma unroll
        for (int i = 0; i < 8; ++i) step(pc[i], u[i]);
        if (k + 1 < nfull) {
#pragma unroll
            for (int i = 0; i < 8; ++i) pc[i] = pf[i];
        }
        e += 8;
    }
    for (e = rs0 + ((nE * g) >> 3) + nfull * 8; e < ee; ++e) {
        const unsigned p = csr[e];
        const uint2 u = *(const uint2*)(xb + (size_t)(p & 0xffffu) * D + c4);
        step(p, u);
    }
    if (cur >= 0) flush();
    __syncthreads();

    // ---- MFMA dual GEMM: [agg*inv | x](32x256) @ Bt^T(256x128) ----
    const int wave = t >> 6;
    const int lane = t & 63;
    const int ln = lane & 15;
    const int quad = lane >> 4;
    const int mtile = wave & 1;       // rows mtile*16..+15
    const int nt0 = (wave >> 1) * 4;  // 4 n-tiles per wave
    const int mrow = mtile * 16 + ln;
    const int gmr = i0 + mrow;
    const float inv = invL[mrow];

    f32x4 acc4[4] = {f32x4{0.f, 0.f, 0.f, 0.f}, f32x4{0.f, 0.f, 0.f, 0.f},
                     f32x4{0.f, 0.f, 0.f, 0.f}, f32x4{0.f, 0.f, 0.f, 0.f}};

#pragma unroll
    for (int s = 0; s < 4; ++s) {
        const int kb = s * 32 + quad * 8;
        const float* ap = aggL + mrow * LSTR + kb;
        const float4 fa = *(const float4*)ap;
        const float4 fb = *(const float4*)(ap + 4);
        const short8 aA = {(short)f2bf(fa.x * inv), (short)f2bf(fa.y * inv),
                           (short)f2bf(fa.z * inv), (short)f2bf(fa.w * inv),
                           (short)f2bf(fb.x * inv), (short)f2bf(fb.y * inv),
                           (short)f2bf(fb.z * inv), (short)f2bf(fb.w * inv)};
        short8 aX = {0, 0, 0, 0, 0, 0, 0, 0};
        if (gmr < N) aX = *(const short8*)(xb + (size_t)gmr * D + kb);
#pragma unroll
        for (int nt = 0; nt < 4; ++nt) {
            const int n = (nt0 + nt) * 16 + ln;
            const short8 b1 = *(const short8*)(Bt + n * 256 + kb);
            const short8 b2 = *(const short8*)(Bt + n * 256 + 128 + kb);
            acc4[nt] = __builtin_amdgcn_mfma_f32_16x16x32_bf16(aA, b1, acc4[nt],
                                                               0, 0, 0);
            acc4[nt] = __builtin_amdgcn_mfma_f32_16x16x32_bf16(aX, b2, acc4[nt],
                                                               0, 0, 0);
        }
    }

    // ---- epilogue: C/D layout col=lane&15, row=quad*4+reg ----
    float biasv[4], woutv[4];
#pragma unroll
    for (int nt = 0; nt < 4; ++nt) {
        const int col = (nt0 + nt) * 16 + ln;
        biasv[nt] = bl[col];
        if (HEAD) woutv[nt] = Wout[col];
    }

    if (!HEAD) {
#pragma unroll
        for (int r = 0; r < 4; ++r) {
            const int gr = i0 + mtile * 16 + quad * 4 + r;
            if (gr < N) {
#pragma unroll
                for (int nt = 0; nt < 4; ++nt) {
                    const int col = (nt0 + nt) * 16 + ln;
                    const float v = fmaxf(acc4[nt][r] + biasv[nt], 0.f);
                    hb_out[(size_t)gr * D + col] = f2bf(v);
                }
            }
        }
    } else {
        const float b0 = bout[0];
#pragma unroll
        for (int r = 0; r < 4; ++r) {
            const int row = mtile * 16 + quad * 4 + r;
            float p = 0.f;
#pragma unroll
            for (int nt = 0; nt < 4; ++nt) {
                const float v = fmaxf(acc4[nt][r] + biasv[nt], 0.f);
                p += v * woutv[nt];
            }
            p += __shfl_xor(p, 1);
            p += __shfl_xor(p, 2);
            p += __shfl_xor(p, 4);
            p += __shfl_xor(p, 8);
            if (ln == 0) redH[row * 2 + (wave >> 1)] = p;
        }
        __syncthreads();
        if (t < 32) {
            const int gr = i0 + t;
            if (gr < N) out[gr] = redH[t * 2] + redH[t * 2 + 1] + b0;
        }
    }
}

extern "C" void kernel_launch(void* const* d_in, const int* in_sizes, int n_in,
                              void* d_out, int out_size, void* d_ws,
                              size_t ws_size, hipStream_t stream) {
    const float* x = (const float*)d_in[0];
    const int* ei = (const int*)d_in[1];
    const float* W1l = (const float*)d_in[2];
    const float* b1l = (const float*)d_in[3];
    const float* W1r = (const float*)d_in[4];
    const float* W2l = (const float*)d_in[5];
    const float* b2l = (const float*)d_in[6];
    const float* W2r = (const float*)d_in[7];
    const float* Wout = (const float*)d_in[8];
    const float* bout = (const float*)d_in[9];

    const int N = in_sizes[0] / D;
    const int E = in_sizes[1] / 2;
    const int* src = ei;
    const int* dst = ei + E;

    const int nbins = (N + 31) / 32;  // 32-row tiles (= sage blocks), <= 2048
    const size_t Npad = (size_t)((N + 255) & ~255);
    const size_t Epad = (size_t)((E + 255) & ~255);

    int* deg = (int*)d_ws;                       // [Npad]
    int* cursor = deg + Npad;                    // [Npad]
    int* tile_base = cursor + Npad;              // [2052]
    float* invL_g = (float*)(tile_base + 2052);  // [Npad]
    unsigned* csr = (unsigned*)(invL_g + Npad);  // [Epad]
    unsigned short* xb = (unsigned short*)(csr + Epad);
    unsigned short* hb = xb + (size_t)N * D;
    unsigned short* Bt1 = hb + (size_t)N * D;
    unsigned short* Bt2 = Bt1 + 128 * 256;
    float* out = (float*)d_out;

    const int NX2 = N * D / 2;
    const int prep_blocks = (NX2 + 2 * 32768 + 255) / 256;

    hipMemsetAsync(deg, 0, Npad * sizeof(int), stream);
    prep_hist_kernel<<<HB + prep_blocks, 256, 0, stream>>>(
        x, W1l, W1r, W2l, W2r, (unsigned*)xb, Bt1, Bt2, NX2, dst, E, deg);
    scan_kernel<<<1, 1024, 0, stream>>>(deg, N, E, nbins, cursor, tile_base,
                                        invL_g);
    fill_kernel<<<(E + 255) / 256, 256, 0, stream>>>(src, dst, E, cursor, csr);

    sage_kernel<false><<<nbins, 256, 0, stream>>>(
        xb, csr, tile_base, invL_g, Bt1, b1l, nullptr, nullptr, hb, nullptr, N);
    sage_kernel<true><<<nbins, 256, 0, stream>>>(
        hb, csr, tile_base, invL_g, Bt2, b2l, Wout, bout, nullptr, out, N);
}

// Round 2
// 308.367 us; speedup vs baseline: 1.3263x; 1.3263x over previous
//
#include <hip/hip_runtime.h>

#define D 128
#define LSTR 132   // padded LDS row stride (floats)
#define HB 256     // degree-histogram block count
#define SCAN_NPB 4096  // nodes per scan block (256 thr x 16)

typedef __attribute__((ext_vector_type(8))) short short8;
typedef __attribute__((ext_vector_type(4))) float f32x4;

static __device__ __forceinline__ unsigned short f2bf(float f) {
    unsigned u = __float_as_uint(f);
    return (unsigned short)((u + 0x7fffu + ((u >> 16) & 1u)) >> 16);  // RNE
}
static __device__ __forceinline__ float b2f(unsigned short u) {
    return __uint_as_float(((unsigned)u) << 16);
}

// ---------------------------------------------------------------------------
// GraphSAGE (mean) x2 + head. bf16 features (fp32 accumulate).
// Row-sorted CSR via global-atomic counting sort:
//   P1 prep+hist: cast x->bf16, transpose weights; atomicAdd degree hist
//   P2 scan1: per-block (4096 nodes) degree sums -> bsum[13]
//   P3 scan2: per-block prefix over bsum + in-block scan -> cursor[N],
//             tile_base[], invL_g[N]   (grid-parallel; fixes the 110us
//             single-block scan of round 1)
//   P4 fill: pos = atomicAdd(&cursor[dst]) -> csr[pos] = src | dst<<16
// sage: segmented register gather over row-sorted csr + MFMA dual GEMM.
//   GV=0: round-0 gather (known-good). GV=1: raw-uint2 + csr-prefetch gather.
//   Layer1 runs GV0, layer2 runs GV1 -> within-run A/B via rocprof rows.
// d_ws: deg[Npad] | cursor[Npad] | tile_base[2052] | bsum[64] | invL_g[Npad]
//       | csr[Epad] | xb bf16[N*D] | hb bf16[N*D] | Bt1 | Bt2
// ---------------------------------------------------------------------------

// Blocks [0, HB): global-atomic degree histogram. Blocks [HB, ...): prep.
__global__ __launch_bounds__(256) void prep_hist_kernel(
    const float* __restrict__ x, const float* __restrict__ W1l,
    const float* __restrict__ W1r, const float* __restrict__ W2l,
    const float* __restrict__ W2r, unsigned* __restrict__ xb2,
    unsigned short* __restrict__ Bt1, unsigned short* __restrict__ Bt2,
    int NX2, const int* __restrict__ dst, int E, int* __restrict__ deg) {
    const int t = threadIdx.x;
    if (blockIdx.x < HB) {
        const int per = (E + HB - 1) / HB;
        const int lo = blockIdx.x * per;
        const int hi = min(lo + per, E);
        for (int i = lo + t; i < hi; i += 256) atomicAdd(&deg[dst[i]], 1);
        return;
    }
    const int i = (blockIdx.x - HB) * 256 + t;
    if (i < NX2) {
        const float2 v = *(const float2*)(x + 2 * (size_t)i);
        xb2[i] = (unsigned)f2bf(v.x) | ((unsigned)f2bf(v.y) << 16);
    } else if (i < NX2 + 2 * 32768) {
        const int j = i - NX2;
        const int which = j >> 15;  // 0 -> layer1, 1 -> layer2
        const int jj = j & 32767;
        const int n = jj >> 8;
        const int k = jj & 255;
        const float* Wl = which ? W2l : W1l;
        const float* Wr = which ? W2r : W1r;
        const float w = (k < 128) ? Wl[k * 128 + n] : Wr[(k - 128) * 128 + n];
        (which ? Bt2 : Bt1)[jj] = f2bf(w);
    }
}

// Per-block degree sums (block = SCAN_NPB nodes).
__global__ __launch_bounds__(256) void scan1_kernel(const int* __restrict__ deg,
                                                    int N,
                                                    int* __restrict__ bsum) {
    const int t = threadIdx.x;
    const int lo = blockIdx.x * SCAN_NPB + t * 16;
    int s = 0;
    if (lo + 16 <= N) {
        const int4* p = (const int4*)(deg + lo);
#pragma unroll
        for (int i = 0; i < 4; ++i) {
            const int4 v = p[i];
            s += v.x + v.y + v.z + v.w;
        }
    } else {
        for (int i = lo; i < min(lo + 16, N); ++i) s += deg[i];
    }
#pragma unroll
    for (int off = 1; off < 64; off <<= 1) s += __shfl_xor(s, off, 64);
    __shared__ int ws[4];
    if ((t & 63) == 0) ws[t >> 6] = s;
    __syncthreads();
    if (t == 0) bsum[blockIdx.x] = ws[0] + ws[1] + ws[2] + ws[3];
}

// Grid-parallel scan: each block redundantly prefixes bsum (13 values), then
// in-block exclusive scan over its 4096 degrees -> cursor/tile_base/invL.
__global__ __launch_bounds__(256) void scan2_kernel(
    const int* __restrict__ deg, int N, int E, int nbins,
    const int* __restrict__ bsum, int* __restrict__ cursor,
    int* __restrict__ tile_base, float* __restrict__ invL_g) {
    __shared__ int ws[5];
    const int t = threadIdx.x;
    const int b = blockIdx.x;
    if (t == 0) {
        int base = 0;
        for (int i = 0; i < b; ++i) base += bsum[i];
        ws[4] = base;
    }
    const int lo = b * SCAN_NPB + t * 16;
    int d[16];
    int s = 0;
    if (lo + 16 <= N) {
        const int4* p = (const int4*)(deg + lo);
#pragma unroll
        for (int i = 0; i < 4; ++i) {
            const int4 v = p[i];
            d[4 * i + 0] = v.x;
            d[4 * i + 1] = v.y;
            d[4 * i + 2] = v.z;
            d[4 * i + 3] = v.w;
            s += v.x + v.y + v.z + v.w;
        }
    } else {
#pragma unroll
        for (int i = 0; i < 16; ++i) {
            d[i] = (lo + i < N) ? deg[lo + i] : 0;
            s += d[i];
        }
    }
    int sc = s;
#pragma unroll
    for (int off = 1; off < 64; off <<= 1) {
        const int u = __shfl_up(sc, off, 64);
        if ((t & 63) >= off) sc += u;
    }
    if ((t & 63) == 63) ws[t >> 6] = sc;
    __syncthreads();
    int run = ws[4] + sc - s;
    for (int w = 0; w < (t >> 6); ++w) run += ws[w];
#pragma unroll
    for (int i = 0; i < 16; ++i) {
        const int idx = lo + i;
        if (idx < N) {
            cursor[idx] = run;
            if ((idx & 31) == 0) tile_base[idx >> 5] = run;
            invL_g[idx] = 1.0f / fmaxf((float)d[i], 1.0f);
            run += d[i];
        }
    }
    if (b == 0 && t == 0) tile_base[nbins] = E;
}

// Scatter edges straight to final row-sorted position via atomic rank.
__global__ __launch_bounds__(256) void fill_kernel(
    const int* __restrict__ src, const int* __restrict__ dst, int E,
    int* __restrict__ cursor, unsigned* __restrict__ csr) {
    const int i = blockIdx.x * 256 + threadIdx.x;
    if (i < E) {
        const int d = dst[i];
        const int pos = atomicAdd(&cursor[d], 1);
        csr[pos] = (unsigned)src[i] | ((unsigned)d << 16);
    }
}

// Fused: segmented bf16 gather (fp32 acc into LDS) -> MFMA dual GEMM with
// mean applied at A-frag build. HEAD folds the Linear(128,1).
// GV=0: round-0 gather. GV=1: raw-uint2 + csr-prefetch gather (A/B test).
template <bool HEAD, int GV>
__global__ __launch_bounds__(256) void sage_kernel(
    const unsigned short* __restrict__ xb, const unsigned* __restrict__ csr,
    const int* __restrict__ tile_base, const float* __restrict__ invL_g,
    const unsigned short* __restrict__ Bt,  // [128 n][256 k] bf16
    const float* __restrict__ bl, const float* __restrict__ Wout,
    const float* __restrict__ bout, unsigned short* __restrict__ hb_out,
    float* __restrict__ out, int N) {
    __shared__ float aggL[32 * LSTR];
    __shared__ float invL[32];
    __shared__ float redH[64];

    const int b = blockIdx.x;
    const int i0 = b * 32;
    const int t = threadIdx.x;
    const int g = t >> 5;
    const int l = t & 31;
    const int c4 = l << 2;

    for (int i = t; i < 32 * LSTR; i += 256) aggL[i] = 0.f;
    if (t < 32) invL[t] = (i0 + t < N) ? invL_g[i0 + t] : 1.0f;
    __syncthreads();

    // ---- segmented edge-parallel aggregation over row-sorted csr ----
    const int rs0 = tile_base[b];
    const int re0 = tile_base[b + 1];
    const int nE = re0 - rs0;
    int e = rs0 + ((nE * g) >> 3);
    const int ee = rs0 + ((nE * (g + 1)) >> 3);

    float4 acc = make_float4(0.f, 0.f, 0.f, 0.f);

    if (GV == 0) {
        int cur = (e < ee) ? (int)(csr[e] >> 16) - i0 : -1;
        auto load4 = [&](unsigned p) -> float4 {
            const ushort4 u =
                *(const ushort4*)(xb + (size_t)(p & 0xffffu) * D + c4);
            float4 v;
            v.x = b2f(u.x); v.y = b2f(u.y); v.z = b2f(u.z); v.w = b2f(u.w);
            return v;
        };
        auto step = [&](unsigned p, const float4& v) {
            const int r = (int)(p >> 16) - i0;
            if (r != cur) {
                float* q = aggL + cur * LSTR + c4;
                atomicAdd(q + 0, acc.x);
                atomicAdd(q + 1, acc.y);
                atomicAdd(q + 2, acc.z);
                atomicAdd(q + 3, acc.w);
                acc = make_float4(0.f, 0.f, 0.f, 0.f);
                cur = r;
            }
            acc.x += v.x; acc.y += v.y; acc.z += v.z; acc.w += v.w;
        };
        while (e + 8 <= ee) {
            const unsigned p0 = csr[e + 0], p1 = csr[e + 1];
            const unsigned p2 = csr[e + 2], p3 = csr[e + 3];
            const unsigned p4 = csr[e + 4], p5 = csr[e + 5];
            const unsigned p6 = csr[e + 6], p7 = csr[e + 7];
            const float4 v0 = load4(p0), v1 = load4(p1), v2 = load4(p2),
                         v3 = load4(p3), v4 = load4(p4), v5 = load4(p5),
                         v6 = load4(p6), v7 = load4(p7);
            step(p0, v0); step(p1, v1); step(p2, v2); step(p3, v3);
            step(p4, v4); step(p5, v5); step(p6, v6); step(p7, v7);
            e += 8;
        }
        while (e < ee) {
            const unsigned p = csr[e];
            step(p, load4(p));
            ++e;
        }
        if (cur >= 0) {
            float* q = aggL + cur * LSTR + c4;
            atomicAdd(q + 0, acc.x);
            atomicAdd(q + 1, acc.y);
            atomicAdd(q + 2, acc.z);
            atomicAdd(q + 3, acc.w);
        }
    } else {
        int cur = -1;
        auto flush = [&]() {
            float* q = aggL + cur * LSTR + c4;
            atomicAdd(q + 0, acc.x);
            atomicAdd(q + 1, acc.y);
            atomicAdd(q + 2, acc.z);
            atomicAdd(q + 3, acc.w);
        };
        auto step = [&](unsigned p, uint2 u) {
            const int r = (int)(p >> 16) - i0;
            if (r != cur) {
                if (cur >= 0) flush();
                acc = make_float4(0.f, 0.f, 0.f, 0.f);
                cur = r;
            }
            acc.x += __uint_as_float(u.x << 16);
            acc.y += __uint_as_float(u.x & 0xffff0000u);
            acc.z += __uint_as_float(u.y << 16);
            acc.w += __uint_as_float(u.y & 0xffff0000u);
        };
        const int e0 = e;
        const int nfull = (ee - e) >> 3;
        unsigned pc[8];
        if (nfull > 0) {
#pragma unroll
            for (int i = 0; i < 8; ++i) pc[i] = csr[e + i];
        }
        for (int k = 0; k < nfull; ++k) {
            uint2 u[8];
#pragma unroll
            for (int i = 0; i < 8; ++i)
                u[i] = *(const uint2*)(xb + (size_t)(pc[i] & 0xffffu) * D + c4);
            unsigned pf[8];
            if (k + 1 < nfull) {
#pragma unroll
                for (int i = 0; i < 8; ++i) pf[i] = csr[e + 8 + i];
            }
#pragma unroll
            for (int i = 0; i < 8; ++i) step(pc[i], u[i]);
            if (k + 1 < nfull) {
#pragma unroll
                for (int i = 0; i < 8; ++i) pc[i] = pf[i];
            }
            e += 8;
        }
        for (e = e0 + nfull * 8; e < ee; ++e) {
            const unsigned p = csr[e];
            const uint2 u =
                *(const uint2*)(xb + (size_t)(p & 0xffffu) * D + c4);
            step(p, u);
        }
        if (cur >= 0) flush();
    }
    __syncthreads();

    // ---- MFMA dual GEMM: [agg*inv | x](32x256) @ Bt^T(256x128) ----
    const int wave = t >> 6;
    const int lane = t & 63;
    const int ln = lane & 15;
    const int quad = lane >> 4;
    const int mtile = wave & 1;       // rows mtile*16..+15
    const int nt0 = (wave >> 1) * 4;  // 4 n-tiles per wave
    const int mrow = mtile * 16 + ln;
    const int gmr = i0 + mrow;
    const float inv = invL[mrow];

    f32x4 acc4[4] = {f32x4{0.f, 0.f, 0.f, 0.f}, f32x4{0.f, 0.f, 0.f, 0.f},
                     f32x4{0.f, 0.f, 0.f, 0.f}, f32x4{0.f, 0.f, 0.f, 0.f}};

#pragma unroll
    for (int s = 0; s < 4; ++s) {
        const int kb = s * 32 + quad * 8;
        const float* ap = aggL + mrow * LSTR + kb;
        const float4 fa = *(const float4*)ap;
        const float4 fb = *(const float4*)(ap + 4);
        const short8 aA = {(short)f2bf(fa.x * inv), (short)f2bf(fa.y * inv),
                           (short)f2bf(fa.z * inv), (short)f2bf(fa.w * inv),
                           (short)f2bf(fb.x * inv), (short)f2bf(fb.y * inv),
                           (short)f2bf(fb.z * inv), (short)f2bf(fb.w * inv)};
        short8 aX = {0, 0, 0, 0, 0, 0, 0, 0};
        if (gmr < N) aX = *(const short8*)(xb + (size_t)gmr * D + kb);
#pragma unroll
        for (int nt = 0; nt < 4; ++nt) {
            const int n = (nt0 + nt) * 16 + ln;
            const short8 b1 = *(const short8*)(Bt + n * 256 + kb);
            const short8 b2 = *(const short8*)(Bt + n * 256 + 128 + kb);
            acc4[nt] = __builtin_amdgcn_mfma_f32_16x16x32_bf16(aA, b1, acc4[nt],
                                                               0, 0, 0);
            acc4[nt] = __builtin_amdgcn_mfma_f32_16x16x32_bf16(aX, b2, acc4[nt],
                                                               0, 0, 0);
        }
    }

    // ---- epilogue: C/D layout col=lane&15, row=quad*4+reg ----
    float biasv[4], woutv[4];
#pragma unroll
    for (int nt = 0; nt < 4; ++nt) {
        const int col = (nt0 + nt) * 16 + ln;
        biasv[nt] = bl[col];
        if (HEAD) woutv[nt] = Wout[col];
    }

    if (!HEAD) {
#pragma unroll
        for (int r = 0; r < 4; ++r) {
            const int gr = i0 + mtile * 16 + quad * 4 + r;
            if (gr < N) {
#pragma unroll
                for (int nt = 0; nt < 4; ++nt) {
                    const int col = (nt0 + nt) * 16 + ln;
                    const float v = fmaxf(acc4[nt][r] + biasv[nt], 0.f);
                    hb_out[(size_t)gr * D + col] = f2bf(v);
                }
            }
        }
    } else {
        const float b0 = bout[0];
#pragma unroll
        for (int r = 0; r < 4; ++r) {
            const int row = mtile * 16 + quad * 4 + r;
            float p = 0.f;
#pragma unroll
            for (int nt = 0; nt < 4; ++nt) {
                const float v = fmaxf(acc4[nt][r] + biasv[nt], 0.f);
                p += v * woutv[nt];
            }
            p += __shfl_xor(p, 1);
            p += __shfl_xor(p, 2);
            p += __shfl_xor(p, 4);
            p += __shfl_xor(p, 8);
            if (ln == 0) redH[row * 2 + (wave >> 1)] = p;
        }
        __syncthreads();
        if (t < 32) {
            const int gr = i0 + t;
            if (gr < N) out[gr] = redH[t * 2] + redH[t * 2 + 1] + b0;
        }
    }
}

extern "C" void kernel_launch(void* const* d_in, const int* in_sizes, int n_in,
                              void* d_out, int out_size, void* d_ws,
                              size_t ws_size, hipStream_t stream) {
    const float* x = (const float*)d_in[0];
    const int* ei = (const int*)d_in[1];
    const float* W1l = (const float*)d_in[2];
    const float* b1l = (const float*)d_in[3];
    const float* W1r = (const float*)d_in[4];
    const float* W2l = (const float*)d_in[5];
    const float* b2l = (const float*)d_in[6];
    const float* W2r = (const float*)d_in[7];
    const float* Wout = (const float*)d_in[8];
    const float* bout = (const float*)d_in[9];

    const int N = in_sizes[0] / D;
    const int E = in_sizes[1] / 2;
    const int* src = ei;
    const int* dst = ei + E;

    const int nbins = (N + 31) / 32;  // 32-row tiles (= sage blocks), <= 2048
    const size_t Npad = (size_t)((N + 255) & ~255);
    const size_t Epad = (size_t)((E + 255) & ~255);

    int* deg = (int*)d_ws;                       // [Npad]
    int* cursor = deg + Npad;                    // [Npad]
    int* tile_base = cursor + Npad;              // [2052]
    int* bsum = tile_base + 2052;                // [64]
    float* invL_g = (float*)(bsum + 64);         // [Npad]
    unsigned* csr = (unsigned*)(invL_g + Npad);  // [Epad]
    unsigned short* xb = (unsigned short*)(csr + Epad);
    unsigned short* hb = xb + (size_t)N * D;
    unsigned short* Bt1 = hb + (size_t)N * D;
    unsigned short* Bt2 = Bt1 + 128 * 256;
    float* out = (float*)d_out;

    const int NX2 = N * D / 2;
    const int prep_blocks = (NX2 + 2 * 32768 + 255) / 256;
    const int nsb = (N + SCAN_NPB - 1) / SCAN_NPB;

    hipMemsetAsync(deg, 0, Npad * sizeof(int), stream);
    prep_hist_kernel<<<HB + prep_blocks, 256, 0, stream>>>(
        x, W1l, W1r, W2l, W2r, (unsigned*)xb, Bt1, Bt2, NX2, dst, E, deg);
    scan1_kernel<<<nsb, 256, 0, stream>>>(deg, N, bsum);
    scan2_kernel<<<nsb, 256, 0, stream>>>(deg, N, E, nbins, bsum, cursor,
                                          tile_base, invL_g);
    fill_kernel<<<(E + 255) / 256, 256, 0, stream>>>(src, dst, E, cursor, csr);

    sage_kernel<false, 0><<<nbins, 256, 0, stream>>>(
        xb, csr, tile_base, invL_g, Bt1, b1l, nullptr, nullptr, hb, nullptr, N);
    sage_kernel<true, 1><<<nbins, 256, 0, stream>>>(
        hb, csr, tile_base, invL_g, Bt2, b2l, Wout, bout, nullptr, out, N);
}